// Round 3
// baseline (437.803 us; speedup 1.0000x reference)
//
#include <hip/hip_runtime.h>
#include <hip/hip_bf16.h>

// out[b,k,oc,x] = sum_i W[k,oc,i] * in[b,i,k,x] + bias[k,oc]
// B=4096, Cin=Cout=128, K(offsets)=9, X=9.
// Memory-bound: ~295 MB HBM traffic ~47us floor @6.3TB/s.
// R1: XCD swizzle + W direct from global.           (158us)
// R2: deep-MLP staging -> null. Load MLP exonerated. (164us)
// R3: LDS-relayout coalesced stores -> -13%.         (143us)
// R4: kill the gather. One block owns ALL 9 k's of a btile (BT=2):
//     - input read fully contiguous (10x dwordx4/thread from one base,
//       1 touch/line, no L2 sibling re-reads; was ~11 partial-line touches
//       per gather instr x 4-5x L2 amplification),
//     - LDS transpose via compile-time immediate-offset ds_write_b16
//       (wave-uniform h/bb -> zero per-element index VALU, 2-way banks = free),
//     - 9 per-k GEMMs (N=18: 2 col-tiles, 2nd mostly padded - MFMA is at 3%),
//     - per-k R3-style relayout epilogue, stores stream across the k-loop.

#define NB    4096
#define CINC  128
#define COUTC 128
#define NK    9
#define NX    9
#define BT    2
#define ROWF  (NK * NX)            // 81 floats per (b,i) row
#define LDK   136                  // padded i-stride (shorts)
#define KSTR  (18 * LDK)           // 2448 shorts: k-stride in Il
#define OUTK  (COUTC * NX)         // 1152 floats per (b,k)
#define OUTB  (NK * COUTC * NX)    // 10368 floats per b

typedef __attribute__((ext_vector_type(8))) short short8;
typedef __attribute__((ext_vector_type(4))) float floatx4;

struct F4 { float x, y, z, w; };   // 16B payload, 4B-aligned (dwordx4 on gfx9+)

__device__ __forceinline__ short f2bf(float f) {
    union { float f; unsigned u; } v; v.f = f;
    unsigned r = v.u + 0x7fff + ((v.u >> 16) & 1);  // RNE; inputs finite normals
    return (short)(r >> 16);
}

// LDS offset (in shorts, relative to Il + bb*9*LDK + i) for flat kx = k*9+x
__device__ __forceinline__ constexpr int koff(int kx) {
    return (kx / 9) * KSTR + (kx % 9) * LDK;
}

// Load 20 floats (5x dwordx4) from p, transpose-write as bf16 at compile-time
// immediate offsets. KX0 is the flat (k*9+x) index of p[0].
template<int KX0>
__device__ __forceinline__ void stage20(short* lb, const float* p) {
    F4 v[5];
    #pragma unroll
    for (int c = 0; c < 5; ++c) v[c] = *(const F4*)(p + 4 * c);
    #pragma unroll
    for (int c = 0; c < 5; ++c) {
        lb[koff(KX0 + 4 * c + 0)] = f2bf(v[c].x);
        lb[koff(KX0 + 4 * c + 1)] = f2bf(v[c].y);
        lb[koff(KX0 + 4 * c + 2)] = f2bf(v[c].z);
        lb[koff(KX0 + 4 * c + 3)] = f2bf(v[c].w);
    }
}

__global__ __launch_bounds__(512, 6) void GatherVertical_40656160424516_kernel(
    const float* __restrict__ in, const float* __restrict__ w,
    const float* __restrict__ bias, float* __restrict__ out)
{
    // Il: bf16 [k=9][col=b*9+x : 18][i : LDK] = 44064 B (transposed input tile)
    // Ol: f32  [b=2][oc=128][x=9]            =  9216 B (epilogue relayout)
    // total 53280 B -> 3 blocks/CU.
    __shared__ __align__(16) char smem[9 * KSTR * 2 + BT * OUTK * 4];
    short* Il = (short*)smem;
    float* Ol = (float*)(smem + 9 * KSTR * 2);

    const int t = threadIdx.x;
    const int b0 = blockIdx.x * BT;

    const int lane = t & 63;
    const int wv = t >> 6;            // 0..7: wave's 16 oc rows
    const int lc = lane & 15;
    const int quad = lane >> 4;
    const int oc_base = wv * 16;

    // ---- staging: thread owns half of row (b=bb, i): floats [40h, 40h+40+h)
    // h and bb are wave-uniform -> uniform branch, immediate LDS offsets.
    const int r = t & 255;
    const int h = t >> 8;
    const int bb = r >> 7;
    const int i = r & 127;

    const float* rowp = in + ((size_t)(b0 + bb) * CINC + i) * ROWF + 40 * h;
    short* lb = Il + bb * (NX * LDK) + i;

    if (h == 0) {
        stage20<0>(lb, rowp);
        stage20<20>(lb, rowp + 20);
    } else {
        stage20<40>(lb, rowp);
        stage20<60>(lb, rowp + 20);
        lb[koff(80)] = f2bf(rowp[40]);          // 81st element
    }

    // ---- W/bias prefetch for k=0 (L2-resident; latency hides under barrier)
    short8 afrA[4], afrB[4];
    float bsA[4], bsB[4];
    auto loadWB = [&](int k, short8* afr, float* bs) {
        const float* wp = w + k * (COUTC * CINC) + (oc_base + lc) * CINC + quad * 8;
        #pragma unroll
        for (int s = 0; s < 4; ++s) {
            float4 w0 = *(const float4*)(wp + s * 32);
            float4 w1 = *(const float4*)(wp + s * 32 + 4);
            short8 a;
            a[0] = f2bf(w0.x); a[1] = f2bf(w0.y); a[2] = f2bf(w0.z); a[3] = f2bf(w0.w);
            a[4] = f2bf(w1.x); a[5] = f2bf(w1.y); a[6] = f2bf(w1.z); a[7] = f2bf(w1.w);
            afr[s] = a;
        }
        const float* bp = bias + k * COUTC + oc_base + quad * 4;
        #pragma unroll
        for (int rr = 0; rr < 4; ++rr) bs[rr] = bp[rr];
    };
    loadWB(0, afrA, bsA);

    __syncthreads();

    for (int k = 0; k < NK; ++k) {
        if (k < NK - 1) loadWB(k + 1, afrB, bsB);

        // ---- MFMA: M=16 (this wave's oc), K=128, N=18 as 2 col-tiles.
        // B-frag: lane holds B[kk=quad*8+e+32s][n=lc] from Il[k][col][i].
        // Tile1 col=16+lc overruns Il for lc>=2 (reads into Ol region, still
        // inside smem); garbage feeds only output cols 18..31 = never stored.
        floatx4 acc0 = {0.f, 0.f, 0.f, 0.f};
        floatx4 acc1 = {0.f, 0.f, 0.f, 0.f};
        const short* bp = Il + k * KSTR + lc * LDK + quad * 8;
        #pragma unroll
        for (int s = 0; s < 4; ++s) {
            short8 bf0 = *(const short8*)(bp + s * 32);
            short8 bf1 = *(const short8*)(bp + 16 * LDK + s * 32);
            acc0 = __builtin_amdgcn_mfma_f32_16x16x32_bf16(afrA[s], bf0, acc0, 0, 0, 0);
            acc1 = __builtin_amdgcn_mfma_f32_16x16x32_bf16(afrA[s], bf1, acc1, 0, 0, 0);
        }

        if (k > 0) __syncthreads();       // previous copy's Ol reads done

        // ---- scatter acc+bias into Ol[b][oc][x].
        // C/D: col(lane&15) = tile col, row(quad*4+rr) = oc offset.
        {
            int bcp = lc >= 9;
            int x = lc - bcp * 9;
            float* op = Ol + (bcp * COUTC + oc_base + quad * 4) * NX + x;
            #pragma unroll
            for (int rr = 0; rr < 4; ++rr) op[rr * NX] = acc0[rr] + bsA[rr];
            if (lc < 2) {                  // tile1 valid cols: 16,17 -> b=1, x=7,8
                float* op1 = Ol + (COUTC + oc_base + quad * 4) * NX + 7 + lc;
                #pragma unroll
                for (int rr = 0; rr < 4; ++rr) op1[rr * NX] = acc1[rr] + bsA[rr];
            }
        }
        __syncthreads();

        // ---- copy Ol -> out: 2 contiguous 4608B runs (b=0,1) per k.
        // 576 x4-chunks over 512 threads; stores stream across k iterations.
        {
            float* dstb = out + (size_t)b0 * OUTB + k * OUTK;
            int bcp = t >= 288;
            int off = (t - bcp * 288) * 4;
            floatx4 v = *(const floatx4*)(Ol + bcp * OUTK + off);
            *(floatx4*)(dstb + bcp * OUTB + off) = v;
            if (t < 64) {
                int off2 = (224 + t) * 4;
                floatx4 v2 = *(const floatx4*)(Ol + OUTK + off2);
                *(floatx4*)(dstb + OUTB + off2) = v2;
            }
        }

        #pragma unroll
        for (int s = 0; s < 4; ++s) afrA[s] = afrB[s];
        #pragma unroll
        for (int rr = 0; rr < 4; ++rr) bsA[rr] = bsB[rr];
    }
}

extern "C" void kernel_launch(void* const* d_in, const int* in_sizes, int n_in,
                              void* d_out, int out_size, void* d_ws, size_t ws_size,
                              hipStream_t stream) {
    const float* in  = (const float*)d_in[0];
    const float* w   = (const float*)d_in[1];
    const float* bs  = (const float*)d_in[2];
    float* out = (float*)d_out;
    dim3 grid(NB / BT);     // 2048 blocks, each owns one btile x all 9 k
    dim3 block(512);
    GatherVertical_40656160424516_kernel<<<grid, block, 0, stream>>>(in, w, bs, out);
}